// Round 6
// baseline (664.785 us; speedup 1.0000x reference)
//
#include <hip/hip_runtime.h>
#include <hip/hip_cooperative_groups.h>
#include <math.h>

namespace cg = cooperative_groups;

#define NC 32
#define NH 1024
#define NW 1024
#define NTH 128
#define NTW 128
#define NBINS 256
#define NTILES 2048
#define NPIXTOT 33554432
#define TPIX 16384
#define NBLK 1024                     /* 4 blocks/CU on 256 CUs */

/* workspace layout (bytes) */
#define OFF_PSUM 0                    /* double[NBLK]  */
#define OFF_PSQ  8192                 /* double[NBLK]  */
#define OFF_PMIN 16384                /* float[NBLK]   */
#define OFF_PMAX 20480                /* float[NBLK]   */
#define OFF_LUT8 24576                /* u8[NTILES*NBINS] = 512KB */

__global__ __launch_bounds__(256, 4) void k_mega(
    const float* __restrict__ x,
    double* __restrict__ ps, double* __restrict__ ps2,
    float* __restrict__ pmn, float* __restrict__ pmx,
    unsigned char* __restrict__ lut8,
    float* __restrict__ out)
{
    cg::grid_group grid = cg::this_grid();
    const int tid = threadIdx.x;
    const int bid = blockIdx.x;
    const int lane = tid & 63, wid = tid >> 6;

    __shared__ double shs[4], shs2[4];
    __shared__ float shmn[4], shmx[4];
    __shared__ float spar[3];
    __shared__ int sflag;
    __shared__ unsigned lh[4 * NBINS];   /* per-wave private histograms */
    __shared__ int sh[NBINS];
    __shared__ unsigned char slut[4096]; /* [2 tile-rows][8 cols][256]  */

    /* ================= phase 1: partial sum/sumsq/min/max ================ */
    {
        long g = (long)bid * 256 + tid;
        double sa = 0.0, sb = 0.0, s2a = 0.0, s2b = 0.0;
        float mn = INFINITY, mx = -INFINITY;
        const float4* x4 = (const float4*)x;
        const long stride = (long)NBLK * 256;          /* 262144 */
        /* n4 = 8388608 = 32*stride: i+stride always in range */
        for (long i = g; i < (long)(NPIXTOT / 4); i += 2 * stride) {
            float4 v = x4[i];
            float4 u = x4[i + stride];
            float sf  = (v.x + v.y) + (v.z + v.w);
            float s2f = fmaf(v.x, v.x, fmaf(v.y, v.y, fmaf(v.z, v.z, v.w * v.w)));
            float sg  = (u.x + u.y) + (u.z + u.w);
            float s2g = fmaf(u.x, u.x, fmaf(u.y, u.y, fmaf(u.z, u.z, u.w * u.w)));
            sa += (double)sf;  s2a += (double)s2f;
            sb += (double)sg;  s2b += (double)s2g;
            mn = fminf(mn, fminf(fminf(v.x, v.y), fminf(v.z, v.w)));
            mx = fmaxf(mx, fmaxf(fmaxf(v.x, v.y), fmaxf(v.z, v.w)));
            mn = fminf(mn, fminf(fminf(u.x, u.y), fminf(u.z, u.w)));
            mx = fmaxf(mx, fmaxf(fmaxf(u.x, u.y), fmaxf(u.z, u.w)));
        }
        double s = sa + sb, s2 = s2a + s2b;
        for (int o = 32; o; o >>= 1) {
            s  += __shfl_down(s, o);
            s2 += __shfl_down(s2, o);
            mn = fminf(mn, __shfl_down(mn, o));
            mx = fmaxf(mx, __shfl_down(mx, o));
        }
        if (lane == 0) { shs[wid] = s; shs2[wid] = s2; shmn[wid] = mn; shmx[wid] = mx; }
        __syncthreads();
        if (tid == 0) {
            ps[bid]  = shs[0] + shs[1] + shs[2] + shs[3];
            ps2[bid] = shs2[0] + shs2[1] + shs2[2] + shs2[3];
            pmn[bid] = fminf(fminf(shmn[0], shmn[1]), fminf(shmn[2], shmn[3]));
            pmx[bid] = fmaxf(fmaxf(shmx[0], shmx[1]), fmaxf(shmx[2], shmx[3]));
        }
        __threadfence();
    }
    grid.sync();

    /* ============ phase 2: params (redundant/block) + hist + LUT ========= */
    float xmin, inv;
    int mv, flag;
    {
        double s = 0.0, s2 = 0.0;
        float mn = INFINITY, mx = -INFINITY;
        for (int i = tid; i < NBLK; i += 256) {
            s += ps[i]; s2 += ps2[i];
            mn = fminf(mn, pmn[i]); mx = fmaxf(mx, pmx[i]);
        }
        for (int o = 32; o; o >>= 1) {
            s  += __shfl_down(s, o);
            s2 += __shfl_down(s2, o);
            mn = fminf(mn, __shfl_down(mn, o));
            mx = fmaxf(mx, __shfl_down(mx, o));
        }
        if (lane == 0) { shs[wid] = s; shs2[wid] = s2; shmn[wid] = mn; shmx[wid] = mx; }
        __syncthreads();
        if (tid == 0) {
            double S  = shs[0] + shs[1] + shs[2] + shs[3];
            double S2 = shs2[0] + shs2[1] + shs2[2] + shs2[3];
            float MN = fminf(fminf(shmn[0], shmn[1]), fminf(shmn[2], shmn[3]));
            float MX = fmaxf(fmaxf(shmx[0], shmx[1]), fmaxf(shmx[2], shmx[3]));
            const double n = (double)NPIXTOT;
            double var = (S2 - S * S / n) / (n - 1.0);
            double sd = sqrt(var > 0.0 ? var : 0.0);
            double range = (double)MX - (double)MN;
            double ct = sd / range;
            double beta = 10.0 * ct;
            double cl = 1.0 / (1.0 - beta) + beta;
            double mvd = floor(cl * (double)TPIX / (double)NBINS);
            if (mvd < 1.0) mvd = 1.0;
            spar[0] = MN;
            spar[1] = (float)(1.0 / range);
            spar[2] = (float)mvd;
            sflag = (ct < 0.05) ? 1 : 0;
        }
        __syncthreads();
        xmin = spar[0]; inv = spar[1]; mv = (int)spar[2]; flag = sflag;
    }
    /* two tiles per block */
    for (int tt = 0; tt < 2; tt++) {
        int t = bid * 2 + tt;
        __syncthreads();
        #pragma unroll
        for (int w = 0; w < 4; w++) lh[w * NBINS + tid] = 0;
        __syncthreads();
        int c = t >> 6, gy = (t >> 3) & 7, gx = t & 7;
        const float* base = x + ((long)c * NH + (long)gy * NTH) * NW + gx * NTW;
        unsigned* mylh = lh + wid * NBINS;
        #pragma unroll 4
        for (int j = 0; j < 16; j++) {
            int l = j * 256 + tid;
            int th = l >> 5, tw4 = l & 31;
            float4 v = *(const float4*)(base + (long)th * NW + tw4 * 4);
            float z0 = (v.x - xmin) * inv;
            float z1 = (v.y - xmin) * inv;
            float z2 = (v.z - xmin) * inv;
            float z3 = (v.w - xmin) * inv;
            int b0 = (int)(z0 * 256.0f); b0 = b0 < 0 ? 0 : (b0 > 255 ? 255 : b0);
            int b1 = (int)(z1 * 256.0f); b1 = b1 < 0 ? 0 : (b1 > 255 ? 255 : b1);
            int b2 = (int)(z2 * 256.0f); b2 = b2 < 0 ? 0 : (b2 > 255 ? 255 : b2);
            int b3 = (int)(z3 * 256.0f); b3 = b3 < 0 ? 0 : (b3 > 255 ? 255 : b3);
            int d = __builtin_amdgcn_readfirstlane(b0);     /* dominant guess */
            int cnt = (b0 == d) + (b1 == d) + (b2 == d) + (b3 == d);
            #pragma unroll
            for (int m = 1; m < 64; m <<= 1) cnt += __shfl_xor(cnt, m);
            if (lane == 0 && cnt > 0) atomicAdd(&mylh[d], (unsigned)cnt);
            if (b0 != d) atomicAdd(&mylh[b0], 1u);
            if (b1 != d) atomicAdd(&mylh[b1], 1u);
            if (b2 != d) atomicAdd(&mylh[b2], 1u);
            if (b3 != d) atomicAdd(&mylh[b3], 1u);
        }
        __syncthreads();
        int hh = (int)(lh[tid] + lh[NBINS + tid] + lh[2 * NBINS + tid] + lh[3 * NBINS + tid]);
        int clp = hh < mv ? hh : mv;
        sh[tid] = clp;
        __syncthreads();
        for (int o = 1; o < NBINS; o <<= 1) {
            int v = (tid >= o) ? sh[tid - o] : 0;
            __syncthreads();
            sh[tid] += v;
            __syncthreads();
        }
        int total = sh[NBINS - 1];
        int cdfc = sh[tid];
        int excess = TPIX - total;
        int residual = excess & (NBINS - 1);
        int redist = excess >> 8;
        int cdf = cdfc + redist * (tid + 1) + ((tid + 1) < residual ? (tid + 1) : residual);
        float lv = floorf(fminf((float)cdf * 255.0f / 16384.0f, 255.0f));
        int iv = (int)(lv < 0.0f ? 0.0f : lv);
        lut8[t * NBINS + tid] = (unsigned char)iv;
    }
    __threadfence();
    grid.sync();

    /* ================= phase 3: 32 rows per block ======================== */
    {
        int c = bid >> 5;
        int h0 = (bid & 31) << 5;
        int cy0 = -1;
        for (int rr = 0; rr < 32; rr++) {
            int h = h0 + rr;
            float gyf = (h + 0.5f) * (1.0f / NTH) - 0.5f;
            float fy = floorf(gyf);
            float wy = gyf - fy;
            int y0 = (int)fy; y0 = y0 < 0 ? 0 : (y0 > 7 ? 7 : y0);
            int y1 = y0 + 1 > 7 ? 7 : y0 + 1;
            if (y0 != cy0) {           /* (y0,y1) pair constant within chunk */
                __syncthreads();
                const unsigned char* src0 = lut8 + ((long)c * 64 + y0 * 8) * NBINS;
                const unsigned char* src1 = lut8 + ((long)c * 64 + y1 * 8) * NBINS;
                if (tid < 128) {
                    *(uint4*)(slut + tid * 16) = *(const uint4*)(src0 + tid * 16);
                } else {
                    int u2 = tid - 128;
                    *(uint4*)(slut + 2048 + u2 * 16) = *(const uint4*)(src1 + u2 * 16);
                }
                __syncthreads();
                cy0 = y0;
            }
            long p = ((long)c << 20) + ((long)h << 10) + tid * 4;
            float4 v = *(const float4*)(x + p);
            float zv[4] = {v.x, v.y, v.z, v.w};
            float o4[4];
            #pragma unroll
            for (int k = 0; k < 4; k++) {
                float z = (zv[k] - xmin) * inv;
                float val;
                if (flag) {
                    int wk = tid * 4 + k;
                    float gxc = (wk + 0.5f) * (1.0f / NTW) - 0.5f;
                    float fx = floorf(gxc);
                    float wx = gxc - fx;
                    int x0 = (int)fx; x0 = x0 < 0 ? 0 : (x0 > 7 ? 7 : x0);
                    int x1 = x0 + 1 > 7 ? 7 : x0 + 1;
                    int b = (int)(z * 255.0f);
                    b = b < 0 ? 0 : (b > 255 ? 255 : b);
                    float l00 = (float)slut[x0 * NBINS + b];
                    float l01 = (float)slut[x1 * NBINS + b];
                    float l10 = (float)slut[2048 + x0 * NBINS + b];
                    float l11 = (float)slut[2048 + x1 * NBINS + b];
                    float top = l00 * (1.0f - wx) + l01 * wx;
                    float bot = l10 * (1.0f - wx) + l11 * wx;
                    val = (top * (1.0f - wy) + bot * wy) * (1.0f / 255.0f);
                } else {
                    val = z;
                }
                o4[k] = log2f(1.0f + val);
            }
            *(float4*)(out + p) = make_float4(o4[0], o4[1], o4[2], o4[3]);
        }
    }
}

extern "C" void kernel_launch(void* const* d_in, const int* in_sizes, int n_in,
                              void* d_out, int out_size, void* d_ws, size_t ws_size,
                              hipStream_t stream) {
    const float* x = (const float*)d_in[0];
    float* out = (float*)d_out;
    char* ws = (char*)d_ws;
    double* ps   = (double*)(ws + OFF_PSUM);
    double* ps2  = (double*)(ws + OFF_PSQ);
    float* pmn   = (float*)(ws + OFF_PMIN);
    float* pmx   = (float*)(ws + OFF_PMAX);
    unsigned char* lut8 = (unsigned char*)(ws + OFF_LUT8);

    void* args[] = { (void*)&x, (void*)&ps, (void*)&ps2, (void*)&pmn,
                     (void*)&pmx, (void*)&lut8, (void*)&out };
    hipLaunchCooperativeKernel((const void*)k_mega, dim3(NBLK), dim3(256),
                               args, 0, stream);
}

// Round 7
// 306.915 us; speedup vs baseline: 2.1660x; 2.1660x over previous
//
#include <hip/hip_runtime.h>
#include <math.h>

#define NC 32
#define NH 1024
#define NW 1024
#define NTH 128
#define NTW 128
#define NBINS 256
#define NTILES (NC*8*8)              /* 2048 */
#define NPIXTOT (NC*NH*NW)           /* 33554432 */
#define TPIX (NTH*NTW)               /* 16384 */

/* workspace layout (bytes) */
#define OFF_PSUM   0                          /* double[2048] */
#define OFF_PSQ    16384                      /* double[2048] */
#define OFF_PMIN   32768                      /* float[2048]  */
#define OFF_PMAX   40960                      /* float[2048]  */
#define OFF_PARAMS 49152                      /* float[16]    */
#define OFF_LUT8   65536                      /* u8[NTILES*NBINS] = 512KB */

/* ---------------- kernel 1: fused sum/sumsq/min/max partial reduce ------- */
/* 4 independent load+accumulate chains per outer iter -> 4x MLP.           */
__global__ __launch_bounds__(256) void k_reduce(const float* __restrict__ x,
                                                double* __restrict__ ps,
                                                double* __restrict__ ps2,
                                                float* __restrict__ pmn,
                                                float* __restrict__ pmx) {
    int tid = threadIdx.x;
    long g = (long)blockIdx.x * 256 + tid;
    double sA = 0.0, sB = 0.0, sC = 0.0, sD = 0.0;
    double qA = 0.0, qB = 0.0, qC = 0.0, qD = 0.0;
    float mn = INFINITY, mx = -INFINITY;
    const float4* x4 = (const float4*)x;
    const long S = (long)2048 * 256;          /* 524288; n4 = 16*S */
    for (long i = g; i < (long)(NPIXTOT / 4); i += 4 * S) {
        float4 a = x4[i];
        float4 b = x4[i + S];
        float4 c = x4[i + 2 * S];
        float4 d = x4[i + 3 * S];
        sA += (double)((a.x + a.y) + (a.z + a.w));
        qA += (double)fmaf(a.x, a.x, fmaf(a.y, a.y, fmaf(a.z, a.z, a.w * a.w)));
        sB += (double)((b.x + b.y) + (b.z + b.w));
        qB += (double)fmaf(b.x, b.x, fmaf(b.y, b.y, fmaf(b.z, b.z, b.w * b.w)));
        sC += (double)((c.x + c.y) + (c.z + c.w));
        qC += (double)fmaf(c.x, c.x, fmaf(c.y, c.y, fmaf(c.z, c.z, c.w * c.w)));
        sD += (double)((d.x + d.y) + (d.z + d.w));
        qD += (double)fmaf(d.x, d.x, fmaf(d.y, d.y, fmaf(d.z, d.z, d.w * d.w)));
        mn = fminf(mn, fminf(fminf(fminf(a.x, a.y), fminf(a.z, a.w)),
                             fminf(fminf(b.x, b.y), fminf(b.z, b.w))));
        mn = fminf(mn, fminf(fminf(fminf(c.x, c.y), fminf(c.z, c.w)),
                             fminf(fminf(d.x, d.y), fminf(d.z, d.w))));
        mx = fmaxf(mx, fmaxf(fmaxf(fmaxf(a.x, a.y), fmaxf(a.z, a.w)),
                             fmaxf(fmaxf(b.x, b.y), fmaxf(b.z, b.w))));
        mx = fmaxf(mx, fmaxf(fmaxf(fmaxf(c.x, c.y), fmaxf(c.z, c.w)),
                             fmaxf(fmaxf(d.x, d.y), fmaxf(d.z, d.w))));
    }
    double s = (sA + sB) + (sC + sD);
    double s2 = (qA + qB) + (qC + qD);
    for (int o = 32; o; o >>= 1) {
        s  += __shfl_down(s, o);
        s2 += __shfl_down(s2, o);
        mn = fminf(mn, __shfl_down(mn, o));
        mx = fmaxf(mx, __shfl_down(mx, o));
    }
    __shared__ double shs[4], shs2[4];
    __shared__ float shmn[4], shmx[4];
    int wid = tid >> 6, lane = tid & 63;
    if (lane == 0) { shs[wid] = s; shs2[wid] = s2; shmn[wid] = mn; shmx[wid] = mx; }
    __syncthreads();
    if (tid == 0) {
        ps[blockIdx.x]  = shs[0] + shs[1] + shs[2] + shs[3];
        ps2[blockIdx.x] = shs2[0] + shs2[1] + shs2[2] + shs2[3];
        pmn[blockIdx.x] = fminf(fminf(shmn[0], shmn[1]), fminf(shmn[2], shmn[3]));
        pmx[blockIdx.x] = fmaxf(fmaxf(shmx[0], shmx[1]), fmaxf(shmx[2], shmx[3]));
    }
}

/* -- kernel 2: per-block redundant params + histogram + clip/scan -> LUT -- */
__global__ __launch_bounds__(256) void k_histlut(const float* __restrict__ x,
                                                 const double* __restrict__ ps,
                                                 const double* __restrict__ ps2,
                                                 const float* __restrict__ pmn,
                                                 const float* __restrict__ pmx,
                                                 float* __restrict__ params,
                                                 unsigned char* __restrict__ lut8) {
    __shared__ unsigned lh[4 * NBINS];   /* 4 per-wave private histograms */
    __shared__ int sh[NBINS];
    __shared__ double shs[4], shs2[4];
    __shared__ float shmn[4], shmx[4], spar[4];
    int tid = threadIdx.x;
    int t = blockIdx.x;
    int lane = tid & 63;
    int wid = tid >> 6;

    /* ---- per-block redundant final reduce + params (L2-hot, ~us) ---- */
    double s = 0.0, s2 = 0.0;
    float mn = INFINITY, mx = -INFINITY;
    for (int i = tid; i < 2048; i += 256) {
        s += ps[i]; s2 += ps2[i];
        mn = fminf(mn, pmn[i]); mx = fmaxf(mx, pmx[i]);
    }
    for (int o = 32; o; o >>= 1) {
        s  += __shfl_down(s, o);
        s2 += __shfl_down(s2, o);
        mn = fminf(mn, __shfl_down(mn, o));
        mx = fmaxf(mx, __shfl_down(mx, o));
    }
    if (lane == 0) { shs[wid] = s; shs2[wid] = s2; shmn[wid] = mn; shmx[wid] = mx; }
    __syncthreads();
    if (tid == 0) {
        double S  = shs[0] + shs[1] + shs[2] + shs[3];
        double S2 = shs2[0] + shs2[1] + shs2[2] + shs2[3];
        float MN = fminf(fminf(shmn[0], shmn[1]), fminf(shmn[2], shmn[3]));
        float MX = fmaxf(fmaxf(shmx[0], shmx[1]), fmaxf(shmx[2], shmx[3]));
        const double n = (double)NPIXTOT;
        double var = (S2 - S * S / n) / (n - 1.0);
        double sd = sqrt(var > 0.0 ? var : 0.0);
        double range = (double)MX - (double)MN;
        double ct = sd / range;
        int flag = (ct < 0.05) ? 1 : 0;
        double beta = 10.0 * ct;
        double cl = 1.0 / (1.0 - beta) + beta;
        double mv = floor(cl * (double)TPIX / (double)NBINS);
        if (mv < 1.0) mv = 1.0;
        spar[0] = MN;
        spar[1] = (float)(1.0 / range);
        spar[2] = (float)mv;
        if (t == 0) {
            params[0] = MN;
            params[1] = (float)(1.0 / range);
            params[2] = (float)mv;
            ((int*)params)[3] = flag;
        }
    }
    #pragma unroll
    for (int w = 0; w < 4; w++) lh[w * NBINS + tid] = 0;
    __syncthreads();
    float xmin = spar[0], inv = spar[1];
    int mv = (int)spar[2];

    /* ---- histogram: dominant-bin wave aggregation ---- */
    int c = t >> 6, gy = (t >> 3) & 7, gx = t & 7;
    const float* base = x + ((long)c * NH + (long)gy * NTH) * NW + gx * NTW;
    unsigned* mylh = lh + wid * NBINS;
    #pragma unroll 4
    for (int j = 0; j < 16; j++) {
        int l = j * 256 + tid;
        int th = l >> 5, tw4 = l & 31;
        float4 v = *(const float4*)(base + (long)th * NW + tw4 * 4);
        int b0 = (int)((v.x - xmin) * inv * 256.0f); b0 = b0 < 0 ? 0 : (b0 > 255 ? 255 : b0);
        int b1 = (int)((v.y - xmin) * inv * 256.0f); b1 = b1 < 0 ? 0 : (b1 > 255 ? 255 : b1);
        int b2 = (int)((v.z - xmin) * inv * 256.0f); b2 = b2 < 0 ? 0 : (b2 > 255 ? 255 : b2);
        int b3 = (int)((v.w - xmin) * inv * 256.0f); b3 = b3 < 0 ? 0 : (b3 > 255 ? 255 : b3);
        int d = __builtin_amdgcn_readfirstlane(b0);
        int cnt = (b0 == d) + (b1 == d) + (b2 == d) + (b3 == d);
        #pragma unroll
        for (int m = 1; m < 64; m <<= 1) cnt += __shfl_xor(cnt, m);
        if (lane == 0 && cnt > 0) atomicAdd(&mylh[d], (unsigned)cnt);
        if (b0 != d) atomicAdd(&mylh[b0], 1u);
        if (b1 != d) atomicAdd(&mylh[b1], 1u);
        if (b2 != d) atomicAdd(&mylh[b2], 1u);
        if (b3 != d) atomicAdd(&mylh[b3], 1u);
    }
    __syncthreads();

    /* ---- merge, clip, scan, emit u8 LUT ---- */
    int h = (int)(lh[tid] + lh[NBINS + tid] + lh[2 * NBINS + tid] + lh[3 * NBINS + tid]);
    int cl = h < mv ? h : mv;
    sh[tid] = cl;
    __syncthreads();
    for (int o = 1; o < NBINS; o <<= 1) {
        int v = (tid >= o) ? sh[tid - o] : 0;
        __syncthreads();
        sh[tid] += v;
        __syncthreads();
    }
    int total = sh[NBINS - 1];
    int cdfc = sh[tid];
    int excess = TPIX - total;
    int residual = excess & (NBINS - 1);
    int redist = excess >> 8;
    int cdf = cdfc + redist * (tid + 1) + ((tid + 1) < residual ? (tid + 1) : residual);
    float lv = floorf(fminf((float)cdf * 255.0f / 16384.0f, 255.0f));
    int iv = (int)(lv < 0.0f ? 0.0f : lv);
    lut8[t * NBINS + tid] = (unsigned char)iv;
}

/* ---------------- kernel 3: bilinear LUT interp + log2(1+x) -------------- */
/* One block per 4-row group (band-aligned: (y0,y1) uniform across group).  */
/* All 4 row loads issued upfront -> 4x MLP; x-dir coords hoisted.          */
__global__ __launch_bounds__(256) void k_out(const float* __restrict__ x,
                                             const float* __restrict__ params,
                                             const unsigned char* __restrict__ lut8,
                                             float* __restrict__ out) {
    __shared__ unsigned char slut[4096];  /* [2 tile-rows][8 cols][256 bins] */
    int tid = threadIdx.x;
    int g = blockIdx.x;                   /* c*256 + row-group */
    int c = g >> 8;
    int h0 = (g & 255) << 2;
    float xmin = params[0], inv = params[1];
    int flag = ((const int*)params)[3];
    /* band-uniform y0/y1 from first row of group */
    float gy0 = (h0 + 0.5f) * (1.0f / NTH) - 0.5f;
    float fy0 = floorf(gy0);
    int y0 = (int)fy0; y0 = y0 < 0 ? 0 : (y0 > 7 ? 7 : y0);
    int y1 = y0 + 1 > 7 ? 7 : y0 + 1;
    const unsigned char* src0 = lut8 + ((long)c * 64 + y0 * 8) * NBINS;
    const unsigned char* src1 = lut8 + ((long)c * 64 + y1 * 8) * NBINS;
    if (tid < 128) {
        *(uint4*)(slut + tid * 16) = *(const uint4*)(src0 + tid * 16);
    } else {
        int u = tid - 128;
        *(uint4*)(slut + 2048 + u * 16) = *(const uint4*)(src1 + u * 16);
    }
    /* issue all 4 row loads before the barrier (independent of staging) */
    const float* base = x + ((long)c << 20) + ((long)h0 << 10) + tid * 4;
    float4 v0 = *(const float4*)(base);
    float4 v1 = *(const float4*)(base + 1024);
    float4 v2 = *(const float4*)(base + 2048);
    float4 v3 = *(const float4*)(base + 3072);
    /* x-direction coords: same for all 4 rows */
    int xo0[4], xo1[4]; float wx[4];
    #pragma unroll
    for (int k = 0; k < 4; k++) {
        int wk = tid * 4 + k;
        float gxc = (wk + 0.5f) * (1.0f / NTW) - 0.5f;
        float fx = floorf(gxc);
        wx[k] = gxc - fx;
        int xx = (int)fx; xx = xx < 0 ? 0 : (xx > 7 ? 7 : xx);
        xo0[k] = xx * NBINS;
        xo1[k] = (xx + 1 > 7 ? 7 : xx + 1) * NBINS;
    }
    __syncthreads();
    float4 vv[4] = {v0, v1, v2, v3};
    #pragma unroll
    for (int r = 0; r < 4; r++) {
        int h = h0 + r;
        float gyf = (h + 0.5f) * (1.0f / NTH) - 0.5f;
        float wy = gyf - floorf(gyf);
        float4 v = vv[r];
        float zf[4] = {v.x, v.y, v.z, v.w};
        float o4[4];
        #pragma unroll
        for (int k = 0; k < 4; k++) {
            float z = (zf[k] - xmin) * inv;
            float val;
            if (flag) {
                int b = (int)(z * 255.0f);
                b = b < 0 ? 0 : (b > 255 ? 255 : b);
                float l00 = (float)slut[xo0[k] + b];
                float l01 = (float)slut[xo1[k] + b];
                float l10 = (float)slut[2048 + xo0[k] + b];
                float l11 = (float)slut[2048 + xo1[k] + b];
                float top = l00 * (1.0f - wx[k]) + l01 * wx[k];
                float bot = l10 * (1.0f - wx[k]) + l11 * wx[k];
                val = (top * (1.0f - wy) + bot * wy) * (1.0f / 255.0f);
            } else {
                val = z;
            }
            o4[k] = __log2f(1.0f + val);
        }
        *(float4*)(out + ((long)c << 20) + ((long)h << 10) + tid * 4) =
            make_float4(o4[0], o4[1], o4[2], o4[3]);
    }
}

extern "C" void kernel_launch(void* const* d_in, const int* in_sizes, int n_in,
                              void* d_out, int out_size, void* d_ws, size_t ws_size,
                              hipStream_t stream) {
    const float* x = (const float*)d_in[0];
    float* out = (float*)d_out;
    char* ws = (char*)d_ws;
    double* ps   = (double*)(ws + OFF_PSUM);
    double* ps2  = (double*)(ws + OFF_PSQ);
    float* pmn   = (float*)(ws + OFF_PMIN);
    float* pmx   = (float*)(ws + OFF_PMAX);
    float* params= (float*)(ws + OFF_PARAMS);
    unsigned char* lut8 = (unsigned char*)(ws + OFF_LUT8);

    k_reduce<<<2048, 256, 0, stream>>>(x, ps, ps2, pmn, pmx);
    k_histlut<<<NTILES, 256, 0, stream>>>(x, ps, ps2, pmn, pmx, params, lut8);
    k_out<<<NC * 256, 256, 0, stream>>>(x, params, lut8, out);
}

// Round 8
// 295.520 us; speedup vs baseline: 2.2495x; 1.0386x over previous
//
#include <hip/hip_runtime.h>
#include <math.h>

#define NC 32
#define NH 1024
#define NW 1024
#define NTH 128
#define NTW 128
#define NBINS 256
#define NTILES (NC*8*8)              /* 2048 */
#define NPIXTOT (NC*NH*NW)           /* 33554432 */
#define TPIX (NTH*NTW)               /* 16384 */

/* workspace layout (bytes) */
#define OFF_PSUM   0                          /* double[2048] */
#define OFF_PSQ    16384                      /* double[2048] */
#define OFF_PMIN   32768                      /* float[2048]  */
#define OFF_PMAX   40960                      /* float[2048]  */
#define OFF_PARAMS 49152                      /* float[16]    */
#define OFF_LUT8   65536                      /* u8[NTILES*NBINS] = 512KB */
#define OFF_IDX8   1048576                    /* u8[NPIXTOT] = 32MB */

/* ---------------- kernel 1: fused sum/sumsq/min/max partial reduce ------- */
__global__ __launch_bounds__(256) void k_reduce(const float* __restrict__ x,
                                                double* __restrict__ ps,
                                                double* __restrict__ ps2,
                                                float* __restrict__ pmn,
                                                float* __restrict__ pmx) {
    int tid = threadIdx.x;
    long g = (long)blockIdx.x * 256 + tid;
    double sA = 0.0, sB = 0.0, sC = 0.0, sD = 0.0;
    double qA = 0.0, qB = 0.0, qC = 0.0, qD = 0.0;
    float mn = INFINITY, mx = -INFINITY;
    const float4* x4 = (const float4*)x;
    const long S = (long)2048 * 256;          /* 524288; n4 = 16*S */
    for (long i = g; i < (long)(NPIXTOT / 4); i += 4 * S) {
        float4 a = x4[i];
        float4 b = x4[i + S];
        float4 c = x4[i + 2 * S];
        float4 d = x4[i + 3 * S];
        sA += (double)((a.x + a.y) + (a.z + a.w));
        qA += (double)fmaf(a.x, a.x, fmaf(a.y, a.y, fmaf(a.z, a.z, a.w * a.w)));
        sB += (double)((b.x + b.y) + (b.z + b.w));
        qB += (double)fmaf(b.x, b.x, fmaf(b.y, b.y, fmaf(b.z, b.z, b.w * b.w)));
        sC += (double)((c.x + c.y) + (c.z + c.w));
        qC += (double)fmaf(c.x, c.x, fmaf(c.y, c.y, fmaf(c.z, c.z, c.w * c.w)));
        sD += (double)((d.x + d.y) + (d.z + d.w));
        qD += (double)fmaf(d.x, d.x, fmaf(d.y, d.y, fmaf(d.z, d.z, d.w * d.w)));
        mn = fminf(mn, fminf(fminf(fminf(a.x, a.y), fminf(a.z, a.w)),
                             fminf(fminf(b.x, b.y), fminf(b.z, b.w))));
        mn = fminf(mn, fminf(fminf(fminf(c.x, c.y), fminf(c.z, c.w)),
                             fminf(fminf(d.x, d.y), fminf(d.z, d.w))));
        mx = fmaxf(mx, fmaxf(fmaxf(fmaxf(a.x, a.y), fmaxf(a.z, a.w)),
                             fmaxf(fmaxf(b.x, b.y), fmaxf(b.z, b.w))));
        mx = fmaxf(mx, fmaxf(fmaxf(fmaxf(c.x, c.y), fmaxf(c.z, c.w)),
                             fmaxf(fmaxf(d.x, d.y), fmaxf(d.z, d.w))));
    }
    double s = (sA + sB) + (sC + sD);
    double s2 = (qA + qB) + (qC + qD);
    for (int o = 32; o; o >>= 1) {
        s  += __shfl_down(s, o);
        s2 += __shfl_down(s2, o);
        mn = fminf(mn, __shfl_down(mn, o));
        mx = fmaxf(mx, __shfl_down(mx, o));
    }
    __shared__ double shs[4], shs2[4];
    __shared__ float shmn[4], shmx[4];
    int wid = tid >> 6, lane = tid & 63;
    if (lane == 0) { shs[wid] = s; shs2[wid] = s2; shmn[wid] = mn; shmx[wid] = mx; }
    __syncthreads();
    if (tid == 0) {
        ps[blockIdx.x]  = shs[0] + shs[1] + shs[2] + shs[3];
        ps2[blockIdx.x] = shs2[0] + shs2[1] + shs2[2] + shs2[3];
        pmn[blockIdx.x] = fminf(fminf(shmn[0], shmn[1]), fminf(shmn[2], shmn[3]));
        pmx[blockIdx.x] = fmaxf(fmaxf(shmx[0], shmx[1]), fmaxf(shmx[2], shmx[3]));
    }
}

/* -- kernel 2: params + histogram + b255-index write + clip/scan -> LUT --- */
/* Ballot-3 leader aggregation (r4-best) + u8 bin-index side output so the  */
/* final pass reads 32MB of indices instead of 128MB of floats.             */
__global__ __launch_bounds__(256) void k_histlut(const float* __restrict__ x,
                                                 const double* __restrict__ ps,
                                                 const double* __restrict__ ps2,
                                                 const float* __restrict__ pmn,
                                                 const float* __restrict__ pmx,
                                                 float* __restrict__ params,
                                                 unsigned char* __restrict__ lut8,
                                                 unsigned char* __restrict__ idx8) {
    __shared__ unsigned lh[4 * NBINS];   /* 4 per-wave private histograms */
    __shared__ int sh[NBINS];
    __shared__ double shs[4], shs2[4];
    __shared__ float shmn[4], shmx[4], spar[4];
    int tid = threadIdx.x;
    int t = blockIdx.x;
    int lane = tid & 63;
    int wid = tid >> 6;

    /* ---- per-block redundant final reduce + params (L2-hot) ---- */
    double s = 0.0, s2 = 0.0;
    float mn = INFINITY, mx = -INFINITY;
    for (int i = tid; i < 2048; i += 256) {
        s += ps[i]; s2 += ps2[i];
        mn = fminf(mn, pmn[i]); mx = fmaxf(mx, pmx[i]);
    }
    for (int o = 32; o; o >>= 1) {
        s  += __shfl_down(s, o);
        s2 += __shfl_down(s2, o);
        mn = fminf(mn, __shfl_down(mn, o));
        mx = fmaxf(mx, __shfl_down(mx, o));
    }
    if (lane == 0) { shs[wid] = s; shs2[wid] = s2; shmn[wid] = mn; shmx[wid] = mx; }
    __syncthreads();
    if (tid == 0) {
        double S  = shs[0] + shs[1] + shs[2] + shs[3];
        double S2 = shs2[0] + shs2[1] + shs2[2] + shs2[3];
        float MN = fminf(fminf(shmn[0], shmn[1]), fminf(shmn[2], shmn[3]));
        float MX = fmaxf(fmaxf(shmx[0], shmx[1]), fmaxf(shmx[2], shmx[3]));
        const double n = (double)NPIXTOT;
        double var = (S2 - S * S / n) / (n - 1.0);
        double sd = sqrt(var > 0.0 ? var : 0.0);
        double range = (double)MX - (double)MN;
        double ct = sd / range;
        int flag = (ct < 0.05) ? 1 : 0;
        double beta = 10.0 * ct;
        double cl = 1.0 / (1.0 - beta) + beta;
        double mv = floor(cl * (double)TPIX / (double)NBINS);
        if (mv < 1.0) mv = 1.0;
        spar[0] = MN;
        spar[1] = (float)(1.0 / range);
        spar[2] = (float)mv;
        if (t == 0) {
            params[0] = MN;
            params[1] = (float)(1.0 / range);
            params[2] = (float)mv;
            ((int*)params)[3] = flag;
        }
    }
    #pragma unroll
    for (int w = 0; w < 4; w++) lh[w * NBINS + tid] = 0;
    __syncthreads();
    float xmin = spar[0], inv = spar[1];
    int mv = (int)spar[2];

    /* ---- histogram + index write ---- */
    int c = t >> 6, gy = (t >> 3) & 7, gx = t & 7;
    long tilebase = ((long)c * NH + (long)gy * NTH) * NW + gx * NTW;
    const float* base = x + tilebase;
    unsigned char* ibase = idx8 + tilebase;
    unsigned* mylh = lh + wid * NBINS;
    #pragma unroll 2
    for (int j = 0; j < 16; j++) {
        int l = j * 256 + tid;
        int th = l >> 5, tw4 = l & 31;
        long rowoff = (long)th * NW + tw4 * 4;
        float4 v = *(const float4*)(base + rowoff);
        float z0 = (v.x - xmin) * inv;
        float z1 = (v.y - xmin) * inv;
        float z2 = (v.z - xmin) * inv;
        float z3 = (v.w - xmin) * inv;
        int b0 = (int)(z0 * 256.0f); b0 = b0 < 0 ? 0 : (b0 > 255 ? 255 : b0);
        int b1 = (int)(z1 * 256.0f); b1 = b1 < 0 ? 0 : (b1 > 255 ? 255 : b1);
        int b2 = (int)(z2 * 256.0f); b2 = b2 < 0 ? 0 : (b2 > 255 ? 255 : b2);
        int b3 = (int)(z3 * 256.0f); b3 = b3 < 0 ? 0 : (b3 > 255 ? 255 : b3);
        int i0 = (int)(z0 * 255.0f); i0 = i0 < 0 ? 0 : (i0 > 255 ? 255 : i0);
        int i1 = (int)(z1 * 255.0f); i1 = i1 < 0 ? 0 : (i1 > 255 ? 255 : i1);
        int i2 = (int)(z2 * 255.0f); i2 = i2 < 0 ? 0 : (i2 > 255 ? 255 : i2);
        int i3 = (int)(z3 * 255.0f); i3 = i3 < 0 ? 0 : (i3 > 255 ? 255 : i3);
        *(uchar4*)(ibase + rowoff) = make_uchar4((unsigned char)i0, (unsigned char)i1,
                                                 (unsigned char)i2, (unsigned char)i3);
        int bs[4] = {b0, b1, b2, b3};
        #pragma unroll
        for (int k = 0; k < 4; k++) {
            int b = bs[k];
            unsigned long long alive = __ballot(1);
            #pragma unroll
            for (int r = 0; r < 3; r++) {
                if (!alive) break;                    /* uniform */
                int leader = (int)(__ffsll((long long)alive) - 1);
                int lb = __shfl(b, leader);
                unsigned long long m = __ballot(b == lb) & alive;
                if (lane == leader) atomicAdd(&mylh[lb], (unsigned)__popcll(m));
                alive &= ~m;
            }
            if ((alive >> lane) & 1ull) atomicAdd(&mylh[b], 1u);
        }
    }
    __syncthreads();

    /* ---- merge, clip, scan, emit u8 LUT ---- */
    int h = (int)(lh[tid] + lh[NBINS + tid] + lh[2 * NBINS + tid] + lh[3 * NBINS + tid]);
    int cl = h < mv ? h : mv;
    sh[tid] = cl;
    __syncthreads();
    for (int o = 1; o < NBINS; o <<= 1) {
        int v = (tid >= o) ? sh[tid - o] : 0;
        __syncthreads();
        sh[tid] += v;
        __syncthreads();
    }
    int total = sh[NBINS - 1];
    int cdfc = sh[tid];
    int excess = TPIX - total;
    int residual = excess & (NBINS - 1);
    int redist = excess >> 8;
    int cdf = cdfc + redist * (tid + 1) + ((tid + 1) < residual ? (tid + 1) : residual);
    float lv = floorf(fminf((float)cdf * 255.0f / 16384.0f, 255.0f));
    int iv = (int)(lv < 0.0f ? 0.0f : lv);
    lut8[t * NBINS + tid] = (unsigned char)iv;
}

/* ---------------- kernel 3: bilinear LUT interp + log2(1+x) -------------- */
/* One block per 4-row group. flag=1 path reads the 32MB u8 index array     */
/* (4x less traffic than re-reading x); flag=0 path falls back to x.        */
__global__ __launch_bounds__(256) void k_out(const float* __restrict__ x,
                                             const float* __restrict__ params,
                                             const unsigned char* __restrict__ lut8,
                                             const unsigned char* __restrict__ idx8,
                                             float* __restrict__ out) {
    __shared__ unsigned char slut[4096];  /* [2 tile-rows][8 cols][256 bins] */
    int tid = threadIdx.x;
    int g = blockIdx.x;                   /* c*256 + row-group */
    int c = g >> 8;
    int h0 = (g & 255) << 2;
    float xmin = params[0], inv = params[1];
    int flag = ((const int*)params)[3];
    float gy0 = (h0 + 0.5f) * (1.0f / NTH) - 0.5f;
    float fy0 = floorf(gy0);
    int y0 = (int)fy0; y0 = y0 < 0 ? 0 : (y0 > 7 ? 7 : y0);
    int y1 = y0 + 1 > 7 ? 7 : y0 + 1;
    const unsigned char* src0 = lut8 + ((long)c * 64 + y0 * 8) * NBINS;
    const unsigned char* src1 = lut8 + ((long)c * 64 + y1 * 8) * NBINS;
    if (tid < 128) {
        *(uint4*)(slut + tid * 16) = *(const uint4*)(src0 + tid * 16);
    } else {
        int u = tid - 128;
        *(uint4*)(slut + 2048 + u * 16) = *(const uint4*)(src1 + u * 16);
    }
    long pbase = ((long)c << 20) + ((long)h0 << 10) + tid * 4;
    uchar4 iv0, iv1, iv2, iv3;
    float4 v0, v1, v2, v3;
    if (flag) {                            /* uniform branch */
        const uchar4* ib = (const uchar4*)(idx8 + pbase);
        iv0 = ib[0]; iv1 = ib[256]; iv2 = ib[512]; iv3 = ib[768];
    } else {
        const float* base = x + pbase;
        v0 = *(const float4*)(base);
        v1 = *(const float4*)(base + 1024);
        v2 = *(const float4*)(base + 2048);
        v3 = *(const float4*)(base + 3072);
    }
    /* x-direction coords: same for all 4 rows */
    int xo0[4], xo1[4]; float wx[4], owx[4];
    #pragma unroll
    for (int k = 0; k < 4; k++) {
        int wk = tid * 4 + k;
        float gxc = (wk + 0.5f) * (1.0f / NTW) - 0.5f;
        float fx = floorf(gxc);
        wx[k] = gxc - fx;
        owx[k] = 1.0f - wx[k];
        int xx = (int)fx; xx = xx < 0 ? 0 : (xx > 7 ? 7 : xx);
        xo0[k] = xx * NBINS;
        xo1[k] = (xx + 1 > 7 ? 7 : xx + 1) * NBINS;
    }
    __syncthreads();
    uchar4 ivv[4] = {iv0, iv1, iv2, iv3};
    float4 vv[4] = {v0, v1, v2, v3};
    #pragma unroll
    for (int r = 0; r < 4; r++) {
        int h = h0 + r;
        float gyf = (h + 0.5f) * (1.0f / NTH) - 0.5f;
        float wy = gyf - floorf(gyf);
        float o4[4];
        if (flag) {
            uchar4 ivr = ivv[r];
            int bb[4] = {ivr.x, ivr.y, ivr.z, ivr.w};
            #pragma unroll
            for (int k = 0; k < 4; k++) {
                int b = bb[k];
                float l00 = (float)slut[xo0[k] + b];
                float l01 = (float)slut[xo1[k] + b];
                float l10 = (float)slut[2048 + xo0[k] + b];
                float l11 = (float)slut[2048 + xo1[k] + b];
                float top = l00 * owx[k] + l01 * wx[k];
                float bot = l10 * owx[k] + l11 * wx[k];
                float val = (top * (1.0f - wy) + bot * wy) * (1.0f / 255.0f);
                o4[k] = __log2f(1.0f + val);
            }
        } else {
            float4 v = vv[r];
            float zf[4] = {v.x, v.y, v.z, v.w};
            #pragma unroll
            for (int k = 0; k < 4; k++) {
                float z = (zf[k] - xmin) * inv;
                o4[k] = __log2f(1.0f + z);
            }
        }
        *(float4*)(out + ((long)c << 20) + ((long)h << 10) + tid * 4) =
            make_float4(o4[0], o4[1], o4[2], o4[3]);
    }
}

extern "C" void kernel_launch(void* const* d_in, const int* in_sizes, int n_in,
                              void* d_out, int out_size, void* d_ws, size_t ws_size,
                              hipStream_t stream) {
    const float* x = (const float*)d_in[0];
    float* out = (float*)d_out;
    char* ws = (char*)d_ws;
    double* ps   = (double*)(ws + OFF_PSUM);
    double* ps2  = (double*)(ws + OFF_PSQ);
    float* pmn   = (float*)(ws + OFF_PMIN);
    float* pmx   = (float*)(ws + OFF_PMAX);
    float* params= (float*)(ws + OFF_PARAMS);
    unsigned char* lut8 = (unsigned char*)(ws + OFF_LUT8);
    unsigned char* idx8 = (unsigned char*)(ws + OFF_IDX8);

    k_reduce<<<2048, 256, 0, stream>>>(x, ps, ps2, pmn, pmx);
    k_histlut<<<NTILES, 256, 0, stream>>>(x, ps, ps2, pmn, pmx, params, lut8, idx8);
    k_out<<<NC * 256, 256, 0, stream>>>(x, params, lut8, idx8, out);
}